// Round 2
// baseline (427.546 us; speedup 1.0000x reference)
//
#include <hip/hip_runtime.h>
#include <math.h>

// Problem dims (fixed by reference)
#define T_DIM 512
#define H_DIM 2048
#define I_DIM 1024
#define E_DIM 16
#define NP    2048          // T*K pairs
#define BM    64            // rows (pairs) per chunk
#define MAXCH 48            // worst-case chunks: NP/BM + E_DIM
#define LIST_OFF 256        // int offset of sorted pair list in ws
#define HWS_OFF  4096       // float offset of h buffer in ws
#define BK    128           // K staged per iteration == scale block size
#define LDK   136           // padded bf16 leading dim (272 B stride -> benign LDS aliasing)

typedef float  float4v __attribute__((ext_vector_type(4)));
typedef short  short8v __attribute__((ext_vector_type(8)));

// f32 -> bf16 round-to-nearest-even (bit pattern) — scalar path (epilogue only)
__device__ __forceinline__ unsigned int bfr(float f) {
    unsigned int u = __builtin_bit_cast(unsigned int, f);
    return (u + 0x7fffu + ((u >> 16) & 1u)) >> 16;
}
// HW packed f32x2 -> bf16x2, RNE (gfx950 v_cvt_pk_bf16_f32). lo=a, hi=b.
__device__ __forceinline__ unsigned int cvt2(float a, float b) {
    unsigned int r;
    asm("v_cvt_pk_bf16_f32 %0, %1, %2" : "=v"(r) : "v"(a), "v"(b));
    return r;
}

// ---- fused routing: count -> plan -> scatter in ONE block ----
__global__ __launch_bounds__(1024) void route_kernel(const int* __restrict__ sel,
                                                     int* __restrict__ meta) {
    __shared__ int cnt[E_DIM];
    __shared__ int wptr[E_DIM];
    int tid = threadIdx.x;
    if (tid < E_DIM) cnt[tid] = 0;
    __syncthreads();
    int p0 = tid, p1 = tid + 1024;
    int e0 = sel[p0], e1 = sel[p1];
    atomicAdd(&cnt[e0], 1);
    atomicAdd(&cnt[e1], 1);
    for (int i = tid; i < MAXCH * BM; i += 1024) meta[LIST_OFF + i] = -1;
    __syncthreads();
    if (tid == 0) {
        int off = 0, ci = 0;
        for (int e = 0; e < E_DIM; ++e) {
            wptr[e] = off;
            int nch = (cnt[e] + BM - 1) / BM;
            for (int j = 0; j < nch; ++j) meta[32 + ci++] = e;
            off += nch * BM;
        }
        for (; ci < MAXCH; ++ci) meta[32 + ci] = -1;
    }
    __syncthreads();
    int pos0 = atomicAdd(&wptr[e0], 1);
    meta[LIST_OFF + pos0] = p0;
    int pos1 = atomicAdd(&wptr[e1], 1);
    meta[LIST_OFF + pos1] = p1;
}

// ---- GEMM 1 (MFMA bf16): h = silu(x.w0d^T) * (x.w1d^T), 64(pairs) x 64(i) tile ----
// 512 threads = 8 waves in a 4(m) x 2(n) grid over the 64x64 tile.
// Register-prefetch double buffer; staging pack via v_cvt_pk_bf16_f32.
// grid: x = itile (16), y = chunk (48) -> same-expert chunks same XCD for L2 reuse.
__global__ __launch_bounds__(512, 4) void gemm01_kernel(
    const float* __restrict__ x, const float* __restrict__ w0g,
    const float* __restrict__ w1g, const float* __restrict__ s0,
    const float* __restrict__ s1, const int* __restrict__ meta,
    unsigned short* __restrict__ hbuf) {
    int e = meta[32 + blockIdx.y];
    if (e < 0) return;
    int itile = blockIdx.x;                 // 0..15 (I/64)
    int tid = threadIdx.x;

    __shared__ unsigned short xs[BM][LDK];
    __shared__ unsigned short as[BM][LDK];
    __shared__ unsigned short bs[BM][LDK];
    __shared__ int prow[BM];
    __shared__ int trow[BM];

    if (tid < BM) {
        int p = meta[LIST_OFF + blockIdx.y * BM + tid];
        prow[tid] = p;
        trow[tid] = p >= 0 ? (p >> 2) : 0;  // token = pair/4
    }
    __syncthreads();

    const int lane = tid & 63;
    const int wid  = tid >> 6;              // 0..7
    const int wm   = wid & 3;               // 16-row m-strip
    const int wn   = wid >> 2;              // 32-col n-half
    const int l15  = lane & 15;
    const int kq   = (lane >> 4) * 8;       // fragment k sub-offset
    const int ib   = itile >> 1;            // i-block (128) for scales

    float4v zero = {0.f, 0.f, 0.f, 0.f};
    float4v accg[2], accu[2];
    accg[0] = accg[1] = accu[0] = accu[1] = zero;

    const int r  = tid >> 3;                // staging row 0..63
    const int c0 = tid & 7;                 // staging float4 phase 0..7
    const float* xrow  = x   + (size_t)trow[r] * H_DIM;
    const float* w0row = w0g + ((size_t)e * I_DIM + itile * 64 + r) * H_DIM;
    const float* w1row = w1g + ((size_t)e * I_DIM + itile * 64 + r) * H_DIM;
    const float* s0p = s0 + ((size_t)e * (I_DIM/128) + ib) * (H_DIM/128);
    const float* s1p = s1 + ((size_t)e * (I_DIM/128) + ib) * (H_DIM/128);

    float4 px[4], pa[4], pb[4];
#pragma unroll
    for (int q = 0; q < 4; ++q) {           // prologue: load chunk 0
        int c4 = (c0 + q * 8) * 4;
        px[q] = *(const float4*)(xrow + c4);
        pa[q] = *(const float4*)(w0row + c4);
        pb[q] = *(const float4*)(w1row + c4);
    }

    for (int hb = 0; hb < H_DIM / BK; ++hb) {     // 16 chunks == 16 scale blocks
        float sg = s0p[hb];
        float su = s1p[hb];
#pragma unroll
        for (int q = 0; q < 4; ++q) {             // regs -> LDS (HW cvt + fold scale)
            int c4 = (c0 + q * 8) * 4;
            *(uint2*)&xs[r][c4] = make_uint2(cvt2(px[q].x, px[q].y), cvt2(px[q].z, px[q].w));
            *(uint2*)&as[r][c4] = make_uint2(cvt2(pa[q].x * sg, pa[q].y * sg),
                                             cvt2(pa[q].z * sg, pa[q].w * sg));
            *(uint2*)&bs[r][c4] = make_uint2(cvt2(pb[q].x * su, pb[q].y * su),
                                             cvt2(pb[q].z * su, pb[q].w * su));
        }
        __syncthreads();
        if (hb + 1 < H_DIM / BK) {                // prefetch next chunk (hidden by MFMA)
            const int h0 = (hb + 1) * BK;
#pragma unroll
            for (int q = 0; q < 4; ++q) {
                int c4 = (c0 + q * 8) * 4;
                px[q] = *(const float4*)(xrow + h0 + c4);
                pa[q] = *(const float4*)(w0row + h0 + c4);
                pb[q] = *(const float4*)(w1row + h0 + c4);
            }
        }
#pragma unroll
        for (int ks = 0; ks < BK / 32; ++ks) {
            int koff = ks * 32 + kq;
            short8v af = *(const short8v*)&xs[wm * 16 + l15][koff];
#pragma unroll
            for (int nt = 0; nt < 2; ++nt) {
                short8v b0 = *(const short8v*)&as[wn * 32 + nt * 16 + l15][koff];
                accg[nt] = __builtin_amdgcn_mfma_f32_16x16x32_bf16(af, b0, accg[nt], 0, 0, 0);
                short8v b1 = *(const short8v*)&bs[wn * 32 + nt * 16 + l15][koff];
                accu[nt] = __builtin_amdgcn_mfma_f32_16x16x32_bf16(af, b1, accu[nt], 0, 0, 0);
            }
        }
        __syncthreads();
    }

    // epilogue: C layout col=lane&15 (i), row=(lane>>4)*4+reg (pair)
    int rowb = wm * 16 + (lane >> 4) * 4;
    int colb = itile * 64 + wn * 32 + l15;
#pragma unroll
    for (int nt = 0; nt < 2; ++nt) {
#pragma unroll
        for (int rg = 0; rg < 4; ++rg) {
            int p = prow[rowb + rg];
            if (p < 0) continue;
            float g = accg[nt][rg], u = accu[nt][rg];
            float h = g / (1.f + __expf(-g)) * u;
            hbuf[(size_t)p * I_DIM + colb + nt * 16] = (unsigned short)bfr(h);
        }
    }
}

// ---- GEMM 2 (MFMA bf16): out[p,:] = (h.w2d^T) * rw[p], 64(pairs) x 64(h) tile ----
// 512 threads = 8 waves, 4(m) x 2(n). grid: x = htile (32), y = chunk (48).
__global__ __launch_bounds__(512, 4) void gemm2_kernel(
    const unsigned short* __restrict__ hbuf, const float* __restrict__ w2g,
    const float* __restrict__ s2, const float* __restrict__ rw,
    const int* __restrict__ meta, float* __restrict__ out) {
    int e = meta[32 + blockIdx.y];
    if (e < 0) return;
    int htile = blockIdx.x;                 // 0..31 (H/64)
    int tid = threadIdx.x;

    __shared__ unsigned short hs[BM][LDK];
    __shared__ unsigned short wsm[BM][LDK];
    __shared__ int prow[BM];

    if (tid < BM) prow[tid] = meta[LIST_OFF + blockIdx.y * BM + tid];
    __syncthreads();

    const int lane = tid & 63;
    const int wid  = tid >> 6;
    const int wm   = wid & 3;
    const int wn   = wid >> 2;
    const int l15  = lane & 15;
    const int kq   = (lane >> 4) * 8;
    const int hbk  = htile >> 1;            // h-block (128) for scales

    float4v zero = {0.f, 0.f, 0.f, 0.f};
    float4v acc[2];
    acc[0] = acc[1] = zero;

    const int r  = tid >> 3;
    const int c0 = tid & 7;
    int pr = prow[r]; if (pr < 0) pr = 0;
    const unsigned short* hrow = hbuf + (size_t)pr * I_DIM;
    const float* wrow = w2g + ((size_t)e * H_DIM + htile * 64 + r) * I_DIM;
    const float* s2p = s2 + ((size_t)e * (H_DIM/128) + hbk) * (I_DIM/128);

    uint2  ph[4];
    float4 pw[4];
#pragma unroll
    for (int q = 0; q < 4; ++q) {           // prologue: load chunk 0
        int c4 = (c0 + q * 8) * 4;
        ph[q] = *(const uint2*)(hrow + c4);
        pw[q] = *(const float4*)(wrow + c4);
    }

    for (int ibk = 0; ibk < I_DIM / BK; ++ibk) {  // 8 chunks == 8 scale blocks
        float sc = s2p[ibk];
#pragma unroll
        for (int q = 0; q < 4; ++q) {
            int c4 = (c0 + q * 8) * 4;
            *(uint2*)&hs[r][c4] = ph[q];          // already bf16
            *(uint2*)&wsm[r][c4] = make_uint2(cvt2(pw[q].x * sc, pw[q].y * sc),
                                              cvt2(pw[q].z * sc, pw[q].w * sc));
        }
        __syncthreads();
        if (ibk + 1 < I_DIM / BK) {               // prefetch next chunk
            const int i0 = (ibk + 1) * BK;
#pragma unroll
            for (int q = 0; q < 4; ++q) {
                int c4 = (c0 + q * 8) * 4;
                ph[q] = *(const uint2*)(hrow + i0 + c4);
                pw[q] = *(const float4*)(wrow + i0 + c4);
            }
        }
#pragma unroll
        for (int ks = 0; ks < BK / 32; ++ks) {
            int koff = ks * 32 + kq;
            short8v af = *(const short8v*)&hs[wm * 16 + l15][koff];
#pragma unroll
            for (int nt = 0; nt < 2; ++nt) {
                short8v bfv = *(const short8v*)&wsm[wn * 32 + nt * 16 + l15][koff];
                acc[nt] = __builtin_amdgcn_mfma_f32_16x16x32_bf16(af, bfv, acc[nt], 0, 0, 0);
            }
        }
        __syncthreads();
    }

    int rowb = wm * 16 + (lane >> 4) * 4;
    int colb = htile * 64 + wn * 32 + l15;
#pragma unroll
    for (int nt = 0; nt < 2; ++nt) {
#pragma unroll
        for (int rg = 0; rg < 4; ++rg) {
            int p = prow[rowb + rg];
            if (p < 0) continue;
            out[(size_t)p * H_DIM + colb + nt * 16] = acc[nt][rg] * rw[p];
        }
    }
}

extern "C" void kernel_launch(void* const* d_in, const int* in_sizes, int n_in,
                              void* d_out, int out_size, void* d_ws, size_t ws_size,
                              hipStream_t stream) {
    const float* x  = (const float*)d_in[0];
    const float* w0 = (const float*)d_in[1];
    const float* w1 = (const float*)d_in[2];
    const float* w2 = (const float*)d_in[3];
    const float* s0 = (const float*)d_in[4];
    const float* s1 = (const float*)d_in[5];
    const float* s2 = (const float*)d_in[6];
    const int* sel  = (const int*)d_in[7];
    const float* rw = (const float*)d_in[8];
    float* out = (float*)d_out;
    int* meta = (int*)d_ws;
    unsigned short* hbuf = (unsigned short*)((float*)d_ws + HWS_OFF);  // 2048*1024 bf16 = 4 MB

    route_kernel<<<1, 1024, 0, stream>>>(sel, meta);
    gemm01_kernel<<<dim3(I_DIM / 64, MAXCH), 512, 0, stream>>>(x, w0, w1, s0, s1, meta, hbuf);
    gemm2_kernel<<<dim3(H_DIM / 64, MAXCH), 512, 0, stream>>>(hbuf, w2, s2, rw, meta, out);
}